// Round 7
// baseline (42.032 us; speedup 1.0000x reference)
//
#include <hip/hip_runtime.h>
#include <hip/hip_bf16.h>

#define OUT_N 8192
#define IN_N  8192
#define QROW  (IN_N / 2)      // 4096 int32 per out row (one widened byte each)
#define NCH   8               // chunks over K
#define CH32  512             // int32 per row per chunk (2 KB contiguous per row)

typedef __attribute__((ext_vector_type(8))) short short8v;  // 8 bf16
typedef __attribute__((ext_vector_type(4))) float f32x4;

__device__ __forceinline__ unsigned int bf16pk(float a, float b) {
    __hip_bfloat162 h = __float22bfloat162_rn(make_float2(a, b));
    unsigned int u;
    __builtin_memcpy(&u, &h, 4);
    return u;
}

// async global->LDS, 16B/lane; LDS dest = wave-uniform base + lane*16 (HW rule)
__device__ __forceinline__ void gld_lds16(const int* gsrc, int* ldst_base) {
    __builtin_amdgcn_global_load_lds(
        (const __attribute__((address_space(1))) void*)gsrc,
        (__attribute__((address_space(3))) void*)ldst_base, 16, 0, 0);
}

#define SBAR()   asm volatile("s_barrier" ::: "memory")
#define VMCNT8() asm volatile("s_waitcnt vmcnt(8)" ::: "memory")
#define VMCNT0() asm volatile("s_waitcnt vmcnt(0)" ::: "memory")
#define SCHED0() __builtin_amdgcn_sched_barrier(0)

// Pre-pass: x fp32 -> bf16 row-major [16][8192] in d_ws (256 KB, L2/L3-hot).
__global__ __launch_bounds__(256) void xconv_kernel(
    const float* __restrict__ x, unsigned short* __restrict__ xb)
{
    int i = (blockIdx.x * 256 + threadIdx.x) * 4;
    float4 v = *(const float4*)(x + i);
    uint2 u = { bf16pk(v.x, v.y), bf16pk(v.z, v.w) };
    *(uint2*)(xb + i) = u;
}

// One block = one 16-out-row tile; 8 waves split each chunk's K 8 ways.
// Staging: wave w DMAs whole rows 2w,2w+1 (1-KB contiguous instrs; each row
// streamed sequentially in 2-KB pieces -> DRAM-friendly). Sync: m201-style
// raw s_barrier + counted OWN vmcnt(8); chunk c+1's 8 vmem ops stay in flight
// across barriers (issue depth 2, vmcnt(0) only on the last chunk).
// LDS read swizzle: global slot j of row R stored at slot (j&64)|((j&63)^R)
// via pre-swizzled per-lane DMA source (LDS dest linear).
__global__ __launch_bounds__(512, 4) void qlin_mfma_kernel(
    const int*            __restrict__ qp,
    const unsigned short* __restrict__ xb,
    const float*          __restrict__ scale,
    const float*          __restrict__ bias,
    float*                __restrict__ out)
{
    __shared__ int   qbuf[2][16][CH32];   // 64 KB double buffer
    __shared__ float red[8][16][17];      // 8.7 KB reduction scratch

    const int t = threadIdx.x;
    const int w = t >> 6;            // wave id -> k-eighth of each chunk
    const int l = t & 63;
    const int g = l >> 4;            // lane group 0..3
    const int r = l & 15;            // A: batch row, B: out row within tile
    const int tile = blockIdx.x;
    const int obase = tile * 16;

    const int R0 = 2 * w;                         // rows this wave stages
    const int* qr0 = qp + (size_t)(obase + R0) * QROW;
    const int* qr1 = qr0 + QROW;
    // pre-swizzled per-lane source slot (16B units) within each 64-slot half
    const int sw0 = (l ^ (R0 & 15)) * 4;          // int32 units
    const int sw1 = (l ^ ((R0 + 1) & 15)) * 4;
    // x bf16 base: elem = r*IN_N + c*1024 + w*128 + s*32 + g*8
    const unsigned short* xbase = xb + (size_t)r * IN_N + w * 128 + g * 8;

    f32x4 acc = {0.f, 0.f, 0.f, 0.f};
    uint4 xr[2][4];

    // issue group(c): 4 x-loads + 4 q-DMAs = 8 vmem ops (order pinned by fences)
#define ISSUE(c_, slot_)                                                      \
    do {                                                                      \
        _Pragma("unroll")                                                     \
        for (int s = 0; s < 4; ++s)                                           \
            xr[slot_][s] = *(const uint4*)(xbase + (c_) * 1024 + s * 32);     \
        gld_lds16(qr0 + (c_) * CH32 + sw0,       &qbuf[(c_) & 1][R0][0]);     \
        gld_lds16(qr0 + (c_) * CH32 + 256 + sw0, &qbuf[(c_) & 1][R0][256]);   \
        gld_lds16(qr1 + (c_) * CH32 + sw1,       &qbuf[(c_) & 1][R0 + 1][0]); \
        gld_lds16(qr1 + (c_) * CH32 + 256 + sw1, &qbuf[(c_) & 1][R0 + 1][256]);\
    } while (0)

    // prologue: chunks 0 and 1 in flight (16 vmem ops)
    ISSUE(0, 0);
    ISSUE(1, 1);

    #pragma unroll    // full unroll: static buffer slots + static vmcnt imms
    for (int c = 0; c < NCH; ++c) {
        if (c < NCH - 1) VMCNT8();   // chunk c resident; c+1 stays in flight
        else             VMCNT0();
        SCHED0();
        SBAR();                      // all waves' chunk-c DMAs resident
        SCHED0();

        const char* bufb = (const char*)&qbuf[c & 1][0][0];
        #pragma unroll
        for (int s = 0; s < 4; ++s) {
            const int j0   = w * 16 + s * 4 + g;              // global 16B slot
            const int slot = (j0 & 64) | ((j0 & 63) ^ r);     // swizzled slot
            const int4 q = *(const int4*)(bufb + r * 2048 + slot * 16);
            // nibble e=2m lo / e=2m+1 hi of byte m; signed; exact in bf16
            uint4 ub = {
                bf16pk((float)((q.x << 28) >> 28), (float)((q.x << 24) >> 28)),
                bf16pk((float)((q.y << 28) >> 28), (float)((q.y << 24) >> 28)),
                bf16pk((float)((q.z << 28) >> 28), (float)((q.z << 24) >> 28)),
                bf16pk((float)((q.w << 28) >> 28), (float)((q.w << 24) >> 28))
            };
            short8v bfrag = __builtin_bit_cast(short8v, ub);
            short8v afrag = __builtin_bit_cast(short8v, xr[c & 1][s]);
            acc = __builtin_amdgcn_mfma_f32_16x16x32_bf16(afrag, bfrag, acc, 0, 0, 0);
        }

        SCHED0();
        SBAR();                      // all waves done reading qbuf[c&1]
        SCHED0();
        if (c + 2 < NCH) ISSUE(c + 2, c & 1);   // overwrite is now safe
    }
#undef ISSUE

    // cross-wave K reduction; D map: col=lane&15 (out), row=(lane>>4)*4+j (batch)
    red[w][g * 4 + 0][r] = acc[0];
    red[w][g * 4 + 1][r] = acc[1];
    red[w][g * 4 + 2][r] = acc[2];
    red[w][g * 4 + 3][r] = acc[3];
    __syncthreads();

    if (t < 256) {
        const int b = t >> 4;            // batch
        const int o = t & 15;            // out within tile
        const int oc = obase + o;
        float v = 0.f;
        #pragma unroll
        for (int i = 0; i < 8; ++i) v += red[i][b][o];
        out[b * OUT_N + oc] = v * scale[oc >> 7] + bias[oc];
    }
}

extern "C" void kernel_launch(void* const* d_in, const int* in_sizes, int n_in,
                              void* d_out, int out_size, void* d_ws, size_t ws_size,
                              hipStream_t stream) {
    (void)in_sizes; (void)n_in; (void)ws_size; (void)out_size;
    const float* x     = (const float*)d_in[0];
    const int*   qp    = (const int*)d_in[1];
    const float* scale = (const float*)d_in[2];
    const float* bias  = (const float*)d_in[3];
    float*       out   = (float*)d_out;
    unsigned short* xb = (unsigned short*)d_ws;    // 256 KB bf16 x

    xconv_kernel<<<dim3((16 * IN_N) / (256 * 4)), dim3(256), 0, stream>>>(x, xb);
    qlin_mfma_kernel<<<dim3(OUT_N / 16), dim3(512), 0, stream>>>(qp, xb, scale, bias, out);
}

// Round 8
// 40.226 us; speedup vs baseline: 1.0449x; 1.0449x over previous
//
#include <hip/hip_runtime.h>
#include <hip/hip_bf16.h>

#define OUT_N 8192
#define IN_N  8192
#define QROW  (IN_N / 2)     // 4096 int32 per out row (one widened byte each)
#define NCH   8              // k sub-chunks per wave
#define CH32  64             // int32 per row per sub-chunk (per wave)

typedef __attribute__((ext_vector_type(8))) short short8v;  // 8 bf16
typedef __attribute__((ext_vector_type(4))) float f32x4;

__device__ __forceinline__ unsigned int bf16pk(float a, float b) {
    __hip_bfloat162 h = __float22bfloat162_rn(make_float2(a, b));
    unsigned int u;
    __builtin_memcpy(&u, &h, 4);
    return u;
}

// async global->LDS, 16B/lane; LDS dest = wave-uniform base + lane*16 (HW rule)
__device__ __forceinline__ void gld_lds16(const int* gsrc, int* ldst_base) {
    __builtin_amdgcn_global_load_lds(
        (const __attribute__((address_space(1))) void*)gsrc,
        (__attribute__((address_space(3))) void*)ldst_base, 16, 0, 0);
}

// One block = one 16-out-row tile; 8 waves split K 8 ways. WAVE-PRIVATE q
// staging (R6 structure — no block barrier in the main loop): each wave DMAs
// the exact 4KB slice it consumes (16 rows x 256B of its k-range) into its own
// LDS double buffer; counted vmcnt(12) keeps next chunk's 12 vmem ops in
// flight (T4), vmcnt(0) only on the last chunk. x fp32 read directly from L2
// and converted inline (xconv pre-pass fused away).
// LDS read swizzle: slot j of row R stored at j^R (global DMA source
// pre-swizzled, LDS dest linear — m173).
__global__ __launch_bounds__(512, 4) void qlin_mfma_kernel(
    const int*   __restrict__ qp,
    const float* __restrict__ x,
    const float* __restrict__ scale,
    const float* __restrict__ bias,
    float*       __restrict__ out)
{
    __shared__ int   qbuf[8][2][16 * CH32];   // 8 waves x 2 x 4KB = 64 KB
    __shared__ float red[8][16][17];          // 8.7 KB reduction scratch

    const int t = threadIdx.x;
    const int w = t >> 6;            // wave id -> k range [w*1024, +1024) elems
    const int l = t & 63;
    const int g = l >> 4;            // lane group 0..3
    const int r = l & 15;            // A: batch row, B: out row within tile
    const int tile = blockIdx.x;
    const int obase = tile * 16;

    // wave-uniform q base for this wave's k-range (int32 units)
    const int* qwbase = qp + (size_t)obase * QROW + w * (QROW / 8);
    const int drow = l >> 4;                      // DMA row sub-index (+4p)
    // x fp32 base: elem = r*IN_N + w*1024 + c*128 + s*32 + g*8
    const float* xwbase = x + (size_t)r * IN_N + w * (IN_N / 8) + g * 8;

    f32x4 acc = {0.f, 0.f, 0.f, 0.f};
    float4 xr[2][4][2];

    // ---- prologue: chunk 0 (8 x-loads then 4 DMAs = 12 vmem ops)
    #pragma unroll
    for (int s = 0; s < 4; ++s) {
        xr[0][s][0] = *(const float4*)(xwbase + s * 32);
        xr[0][s][1] = *(const float4*)(xwbase + s * 32 + 4);
    }
    #pragma unroll
    for (int p = 0; p < 4; ++p) {
        const int row = 4 * p + drow;
        const int j   = (l & 15) ^ (row & 15);    // pre-swizzled source slot
        gld_lds16(qwbase + (size_t)row * QROW + j * 4, &qbuf[w][0][p * 256]);
    }

    #pragma unroll   // full unroll: static buffer indices + static vmcnt imms
    for (int c = 0; c < NCH; ++c) {
        const int cur = c & 1;

        if (c + 1 < NCH) {
            // issue next chunk: x loads FIRST (L2, retire first), then DMAs
            #pragma unroll
            for (int s = 0; s < 4; ++s) {
                xr[cur ^ 1][s][0] = *(const float4*)(xwbase + (c + 1) * 128 + s * 32);
                xr[cur ^ 1][s][1] = *(const float4*)(xwbase + (c + 1) * 128 + s * 32 + 4);
            }
            #pragma unroll
            for (int p = 0; p < 4; ++p) {
                const int row = 4 * p + drow;
                const int j   = (l & 15) ^ (row & 15);
                gld_lds16(qwbase + (size_t)row * QROW + (c + 1) * CH32 + j * 4,
                          &qbuf[w][cur ^ 1][p * 256]);
            }
            // retire chunk c's 12 ops; leave chunk c+1's 12 in flight
            asm volatile("s_waitcnt vmcnt(12)" ::: "memory");
        } else {
            asm volatile("s_waitcnt vmcnt(0)" ::: "memory");
        }
        __builtin_amdgcn_sched_barrier(0);   // rule #18: pin ds_reads below wait

        const char* wb = (const char*)qbuf[w][cur];
        #pragma unroll
        for (int s = 0; s < 4; ++s) {
            // read slot j0 = s*4+g of row r, stored at slot j0^r (2-way = free)
            const int4 q = *(const int4*)(wb + r * 256 + ((((s << 2) + g) ^ r) << 4));
            // nibble e=2m lo / e=2m+1 hi of byte m; signed; exact in bf16
            uint4 ub = {
                bf16pk((float)((q.x << 28) >> 28), (float)((q.x << 24) >> 28)),
                bf16pk((float)((q.y << 28) >> 28), (float)((q.y << 24) >> 28)),
                bf16pk((float)((q.z << 28) >> 28), (float)((q.z << 24) >> 28)),
                bf16pk((float)((q.w << 28) >> 28), (float)((q.w << 24) >> 28))
            };
            short8v bfrag = __builtin_bit_cast(short8v, ub);
            // A-frag: 8 fp32 -> 8 bf16 inline (RNE)
            const float4 xa = xr[cur][s][0], xc = xr[cur][s][1];
            uint4 ua = { bf16pk(xa.x, xa.y), bf16pk(xa.z, xa.w),
                         bf16pk(xc.x, xc.y), bf16pk(xc.z, xc.w) };
            short8v afrag = __builtin_bit_cast(short8v, ua);
            acc = __builtin_amdgcn_mfma_f32_16x16x32_bf16(afrag, bfrag, acc, 0, 0, 0);
        }
    }

    // ---- cross-wave K reduction; D map: col=lane&15 (out), row=(lane>>4)*4+j
    red[w][g * 4 + 0][r] = acc[0];
    red[w][g * 4 + 1][r] = acc[1];
    red[w][g * 4 + 2][r] = acc[2];
    red[w][g * 4 + 3][r] = acc[3];
    __syncthreads();

    if (t < 256) {
        const int b = t >> 4;            // batch
        const int o = t & 15;            // out within tile
        const int oc = obase + o;
        float v = 0.f;
        #pragma unroll
        for (int i = 0; i < 8; ++i) v += red[i][b][o];
        out[b * OUT_N + oc] = v * scale[oc >> 7] + bias[oc];
    }
}

extern "C" void kernel_launch(void* const* d_in, const int* in_sizes, int n_in,
                              void* d_out, int out_size, void* d_ws, size_t ws_size,
                              hipStream_t stream) {
    (void)in_sizes; (void)n_in; (void)d_ws; (void)ws_size; (void)out_size;
    const float* x     = (const float*)d_in[0];
    const int*   qp    = (const int*)d_in[1];
    const float* scale = (const float*)d_in[2];
    const float* bias  = (const float*)d_in[3];
    float*       out   = (float*)d_out;

    qlin_mfma_kernel<<<dim3(OUT_N / 16), dim3(512), 0, stream>>>(qp, x, scale, bias, out);
}